// Round 2
// baseline (721.109 us; speedup 1.0000x reference)
//
#include <hip/hip_runtime.h>
#include <cstdint>

typedef __attribute__((ext_vector_type(8))) __bf16 bf16x8;
typedef __attribute__((ext_vector_type(4))) __bf16 bf16x4;
typedef __attribute__((ext_vector_type(4))) float f32x4;

__device__ __forceinline__ void gld_lds16(const void* g, void* l) {
  __builtin_amdgcn_global_load_lds(
      (const __attribute__((address_space(1))) void*)g,
      (__attribute__((address_space(3))) void*)l, 16, 0, 0);
}

__device__ __forceinline__ float block_sum(float v, float* scr) {
#pragma unroll
  for (int off = 32; off > 0; off >>= 1) v += __shfl_down(v, off, 64);
  const int w = threadIdx.x >> 6;
  __syncthreads();
  if ((threadIdx.x & 63) == 0) scr[w] = v;
  __syncthreads();
  float s = 0.f;
  const int nw = blockDim.x >> 6;
  for (int i = 0; i < nw; ++i) s += scr[i];
  return s;
}

__device__ __forceinline__ float gelu_exact(float x) {
  return 0.5f * x * (1.f + erff(x * 0.70710678118654752f));
}

// ---------------- casts ----------------
__global__ __launch_bounds__(256) void k_cast_bf16(const float* __restrict__ in,
                                                   __bf16* __restrict__ out) {
  const long i = ((long)blockIdx.x * 256 + threadIdx.x) * 4;
  f32x4 v = *(const f32x4*)(in + i);
  bf16x4 o = {(__bf16)v[0], (__bf16)v[1], (__bf16)v[2], (__bf16)v[3]};
  *(bf16x4*)(out + i) = o;
}

__global__ __launch_bounds__(256) void k_cast_pad(const float* __restrict__ in,
                                                  __bf16* __restrict__ out,
                                                  int rows_real, int cols) {
  const long i = ((long)blockIdx.x * 256 + threadIdx.x) * 4;
  const int row = (int)(i / cols);
  const int col = (int)(i % cols);
  bf16x4 o;
  if (row < rows_real) {
    f32x4 v = *(const f32x4*)(in + (long)row * cols + col);
    o = (bf16x4){(__bf16)v[0], (__bf16)v[1], (__bf16)v[2], (__bf16)v[3]};
  } else {
    o = (bf16x4){(__bf16)0.f, (__bf16)0.f, (__bf16)0.f, (__bf16)0.f};
  }
  *(bf16x4*)(out + i) = o;
}

// ---------------- GEMM: C = A @ B^T + bias, epilogue templated ----------------
// A: M x K bf16 row-major; B: N x K bf16 row-major; C: M x Nreal (ldc = Nreal)
// EPI: 0 = f32 store, 1 = bf16 store, 2 = gelu -> bf16,
//      4 = fused self-mod update: supR/supI *= sigmoid(acc+bias)+0.1 (no Cout)
template <int EPI>
__global__ __launch_bounds__(256) void k_gemm_bt(
    const __bf16* __restrict__ A, const __bf16* __restrict__ B,
    const float* __restrict__ bias, void* __restrict__ Cout,
    int M, int N, int K, int Nreal,
    float* __restrict__ supR, float* __restrict__ supI) {
  __shared__ __align__(16) __bf16 As[128 * 32];
  __shared__ __align__(16) __bf16 Bs[128 * 32];
  const int tid = threadIdx.x;
  const int lane = tid & 63;
  const int wid = tid >> 6;
  const int wr = wid >> 1, wc = wid & 1;      // 2x2 wave grid, 64x64 each
  const int m0 = blockIdx.y * 128;
  const int n0 = blockIdx.x * 128;
  const int frow = lane & 15;
  const int fk = (lane >> 4) * 8;
  f32x4 acc[4][4] = {};

  for (int k0 = 0; k0 < K; k0 += 32) {
    const __bf16* Ab = A + (long)m0 * K + k0;
    const __bf16* Bb = B + (long)n0 * K + k0;
#pragma unroll
    for (int q = 0; q < 2; ++q) {
      const int idx = q * 256 + tid;
      const int row = idx >> 2;
      const int col = (idx & 3) * 8;
      gld_lds16(Ab + (long)row * K + col, (char*)As + idx * 16);
      gld_lds16(Bb + (long)row * K + col, (char*)Bs + idx * 16);
    }
    __syncthreads();
    bf16x8 af[4], bfr[4];
#pragma unroll
    for (int i = 0; i < 4; ++i) {
      af[i] = *(const bf16x8*)(As + (wr * 64 + i * 16 + frow) * 32 + fk);
      bfr[i] = *(const bf16x8*)(Bs + (wc * 64 + i * 16 + frow) * 32 + fk);
    }
#pragma unroll
    for (int im = 0; im < 4; ++im)
#pragma unroll
      for (int in = 0; in < 4; ++in)
        acc[im][in] = __builtin_amdgcn_mfma_f32_16x16x32_bf16(af[im], bfr[in],
                                                              acc[im][in], 0, 0, 0);
    __syncthreads();
  }

  const int crow0 = m0 + wr * 64 + (lane >> 4) * 4;
  const int ccol0 = n0 + wc * 64 + (lane & 15);
#pragma unroll
  for (int in = 0; in < 4; ++in) {
    const int col = ccol0 + in * 16;
    if (col >= Nreal) continue;
    const float bv = bias[col];
#pragma unroll
    for (int im = 0; im < 4; ++im) {
#pragma unroll
      for (int r = 0; r < 4; ++r) {
        const long row = crow0 + im * 16 + r;
        const float v = acc[im][in][r] + bv;
        if (EPI == 0) {
          ((float*)Cout)[row * Nreal + col] = v;
        } else if (EPI == 1) {
          ((__bf16*)Cout)[row * Nreal + col] = (__bf16)v;
        } else if (EPI == 2) {
          ((__bf16*)Cout)[row * Nreal + col] = (__bf16)gelu_exact(v);
        } else {
          const float gmul = 1.f / (1.f + expf(-v)) + 0.1f;
          const long ix = row * Nreal + col;
          supR[ix] *= gmul;
          supI[ix] *= gmul;
        }
      }
    }
  }
}

// ---------------- LN (over 1024) + exact gelu -> bf16 ----------------
__global__ __launch_bounds__(256) void k_ln_gelu(const float* __restrict__ y,
                                                 const float* __restrict__ g,
                                                 const float* __restrict__ b,
                                                 __bf16* __restrict__ h) {
  __shared__ float scr[8];
  const int tid = threadIdx.x;
  const long row = blockIdx.x;
  const float* yr = y + row * 1024;
  f32x4 v = *(const f32x4*)(yr + tid * 4);
  float ls = v[0] + v[1] + v[2] + v[3];
  const float mu = block_sum(ls, scr) * (1.f / 1024.f);
  float lss = 0.f;
#pragma unroll
  for (int j = 0; j < 4; ++j) {
    const float d = v[j] - mu;
    lss += d * d;
  }
  const float var = block_sum(lss, scr) * (1.f / 1024.f);
  const float rstd = rsqrtf(var + 1e-5f);
  bf16x4 o;
#pragma unroll
  for (int j = 0; j < 4; ++j) {
    const int c = tid * 4 + j;
    const float t = (v[j] - mu) * rstd * g[c] + b[c];
    o[j] = (__bf16)gelu_exact(t);
  }
  *(bf16x4*)(h + row * 1024 + tid * 4) = o;
}

// ---------------- stage C ----------------
__global__ __launch_bounds__(256) void k_stage_c(
    const __bf16* __restrict__ outb, const float* __restrict__ ln_g,
    const float* __restrict__ ln_b, const float* __restrict__ phases,
    const float* __restrict__ temp, float* __restrict__ supr,
    float* __restrict__ supi, int b0) {
  __shared__ float wrs[3][1024];
  __shared__ float wis[3][1024];
  __shared__ float gbuf[2048];
  __shared__ float scr[8];
  const int tid = threadIdx.x;
  const long b = blockIdx.x;

#pragma unroll 1
  for (int s = 0; s < 3; ++s) {
    const __bf16* src = outb + b * 6144 + s * 2048;
    bf16x8 v8 = *(const bf16x8*)(src + tid * 8);
    float x[8];
#pragma unroll
    for (int j = 0; j < 8; ++j) x[j] = (float)v8[j];
    float ls = 0.f;
#pragma unroll
    for (int j = 0; j < 8; ++j) ls += x[j];
    const float mu = block_sum(ls, scr) * (1.f / 2048.f);
    float lss = 0.f;
#pragma unroll
    for (int j = 0; j < 8; ++j) {
      const float d = x[j] - mu;
      lss += d * d;
    }
    const float var = block_sum(lss, scr) * (1.f / 2048.f);
    const float rstd = rsqrtf(var + 1e-5f);
    const float* lg = ln_g + s * 2048;
    const float* lb = ln_b + s * 2048;
    float nsq = 0.f;
#pragma unroll
    for (int j = 0; j < 8; ++j) {
      const int e = tid * 8 + j;
      const float yv = (x[j] - mu) * rstd * lg[e] + lb[e];
      const float gv = expf(-yv * yv);
      gbuf[e] = gv;
      nsq += gv * gv;
    }
    const float normsq = block_sum(nsq, scr) + 1e-8f; // syncs make gbuf visible
    const float factor = sqrtf(2.25f / normsq);
    const float ph = phases[s];
    const float cs = cosf(ph), sn = sinf(ph);
#pragma unroll
    for (int j = 0; j < 4; ++j) {
      const int h = j * 256 + tid;
      const float a = gbuf[h] * factor;
      const float bb = gbuf[h + 1024] * factor;
      wrs[s][h] = a * cs - bb * sn;
      wis[s][h] = a * sn + bb * cs;
    }
    __syncthreads();
  }

  float mr[4];
  float pmn = 0.f;
#pragma unroll
  for (int j = 0; j < 4; ++j) {
    const int h = j * 256 + tid;
    const float m = (wrs[0][h] + wrs[1][h] + wrs[2][h]) * (1.f / 3.f);
    mr[j] = m;
    pmn += m * m;
  }
  const float mnorm = sqrtf(block_sum(pmn, scr)) + 1e-8f;
  float csim[3];
#pragma unroll 1
  for (int s = 0; s < 3; ++s) {
    float pd = 0.f, pw = 0.f;
#pragma unroll
    for (int j = 0; j < 4; ++j) {
      const int h = j * 256 + tid;
      const float w = wrs[s][h];
      pd += w * mr[j];
      pw += w * w;
    }
    const float dot = block_sum(pd, scr);
    const float wn = sqrtf(block_sum(pw, scr)) + 1e-8f;
    csim[s] = dot / (wn * mnorm);
  }
  const float T = temp[0];
  const float t0 = csim[0] / T, t1 = csim[1] / T, t2 = csim[2] / T;
  const float mx = fmaxf(t0, fmaxf(t1, t2));
  const float e0 = expf(t0 - mx), e1 = expf(t1 - mx), e2 = expf(t2 - mx);
  const float inv = 1.f / (e0 + e1 + e2);
  const float w0 = e0 * inv, w1 = e1 * inv, w2 = e2 * inv;
#pragma unroll
  for (int j = 0; j < 4; ++j) {
    const int h = j * 256 + tid;
    supr[(long)(b0 + b) * 1024 + h] = wrs[0][h] * w0 + wrs[1][h] * w1 + wrs[2][h] * w2;
    supi[(long)(b0 + b) * 1024 + h] = wis[0][h] * w0 + wis[1][h] * w1 + wis[2][h] * w2;
  }
}

// ---------------- mag ----------------
__global__ __launch_bounds__(256) void k_mag(const float* __restrict__ sr,
                                             const float* __restrict__ si,
                                             __bf16* __restrict__ mag) {
  const long i = ((long)blockIdx.x * 256 + threadIdx.x) * 4;
  f32x4 r = *(const f32x4*)(sr + i);
  f32x4 im = *(const f32x4*)(si + i);
  bf16x4 o;
#pragma unroll
  for (int j = 0; j < 4; ++j)
    o[j] = (__bf16)sqrtf(r[j] * r[j] + im[j] * im[j] + 1e-8f);
  *(bf16x4*)(mag + i) = o;
}

// ---------------- top-8 mask + normalize -> probs (bf16) ----------------
__global__ __launch_bounds__(256) void k_topk(const float* __restrict__ supr,
                                              const float* __restrict__ supi,
                                              __bf16* __restrict__ probs) {
  __shared__ float vals[1024];
  __shared__ float redv[4];
  __shared__ int redi[4];
  __shared__ int selidx[8];
  __shared__ float ssum;
  const int tid = threadIdx.x;
  const long b = blockIdx.x;
  float myv[4];
#pragma unroll
  for (int j = 0; j < 4; ++j) {
    const int h = j * 256 + tid;
    const float r = supr[b * 1024 + h];
    const float im = supi[b * 1024 + h];
    const float v = r * r + im * im;
    myv[j] = v;
    vals[h] = v;
  }
  if (tid == 0) ssum = 0.f;
  __syncthreads();
  for (int it = 0; it < 8; ++it) {
    float bv = -1.f;
    int bi = 1 << 30;
#pragma unroll
    for (int j = 0; j < 4; ++j) {
      const int h = j * 256 + tid;
      const float v = vals[h];
      if (v > bv || (v == bv && h < bi)) { bv = v; bi = h; }
    }
#pragma unroll
    for (int off = 32; off > 0; off >>= 1) {
      const float ov = __shfl_down(bv, off, 64);
      const int oi = __shfl_down(bi, off, 64);
      if (ov > bv || (ov == bv && oi < bi)) { bv = ov; bi = oi; }
    }
    if ((tid & 63) == 0) { redv[tid >> 6] = bv; redi[tid >> 6] = bi; }
    __syncthreads();
    if (tid == 0) {
      float fv = redv[0];
      int fi = redi[0];
      for (int w = 1; w < 4; ++w)
        if (redv[w] > fv || (redv[w] == fv && redi[w] < fi)) { fv = redv[w]; fi = redi[w]; }
      selidx[it] = fi;
      vals[fi] = -1.f;
      ssum += fv;
    }
    __syncthreads();
  }
  const float denom = 1.f / (ssum + 1e-8f);
#pragma unroll
  for (int j = 0; j < 4; ++j) {
    const int h = j * 256 + tid;
    float p = 0.f;
#pragma unroll
    for (int t = 0; t < 8; ++t)
      if (selidx[t] == h) p = myv[j] * denom;
    probs[b * 1024 + h] = (__bf16)p;
  }
}

extern "C" void kernel_launch(void* const* d_in, const int* in_sizes, int n_in,
                              void* d_out, int out_size, void* d_ws, size_t ws_size,
                              hipStream_t stream) {
  const float* x      = (const float*)d_in[0];
  const float* proj_w = (const float*)d_in[1];
  const float* proj_b = (const float*)d_in[2];
  const float* ln_p_g = (const float*)d_in[3];
  const float* ln_p_b = (const float*)d_in[4];
  const float* wf_w   = (const float*)d_in[5];
  const float* wf_b   = (const float*)d_in[6];
  const float* ln_g   = (const float*)d_in[7];
  const float* ln_b   = (const float*)d_in[8];
  const float* temperature = (const float*)d_in[9];
  const float* phases = (const float*)d_in[10];
  const float* gate_w = (const float*)d_in[11];
  const float* gate_b = (const float*)d_in[12];
  const float* cls_w1 = (const float*)d_in[13];
  const float* cls_b1 = (const float*)d_in[14];
  const float* cls_w2 = (const float*)d_in[15];
  const float* cls_b2 = (const float*)d_in[16];
  float* out = (float*)d_out;
  (void)in_sizes; (void)n_in; (void)out_size; (void)ws_size;

  // 130MB lifetime-aliased layout (regions never overlap while live):
  //   A [0,32M):   xb (casts,G1)            -> supr (stage_c..topk)
  //   B [32,64M):  y1 (G1,ln) -> outc 24MB (chunk loop) -> magb@+0 / probs@+16M / hid@+0
  //   C [64,96M):  w1b@+0 4MB (casts,G1)    -> supi (stage_c..topk)
  //   [96,108M):   wfwb     [108,124M): hb(h)    [124,130M): gwb,c1b,c2b
  char* ws = (char*)d_ws;
  const size_t MB = 1024 * 1024;
  __bf16* xb    = (__bf16*)(ws + 0);
  float*  supr  = (float*)(ws + 0);
  float*  y1    = (float*)(ws + 32 * MB);
  __bf16* outc  = (__bf16*)(ws + 32 * MB);
  __bf16* magb  = (__bf16*)(ws + 32 * MB);
  __bf16* hid   = (__bf16*)(ws + 32 * MB);
  __bf16* probs = (__bf16*)(ws + 48 * MB);
  __bf16* w1b   = (__bf16*)(ws + 64 * MB);
  float*  supi  = (float*)(ws + 64 * MB);
  __bf16* wfwb  = (__bf16*)(ws + 96 * MB);
  __bf16* hb    = (__bf16*)(ws + 108 * MB);
  __bf16* gwb   = (__bf16*)(ws + 124 * MB);
  __bf16* c1b   = (__bf16*)(ws + 126 * MB);
  __bf16* c2b   = (__bf16*)(ws + 128 * MB);

  // casts
  k_cast_bf16<<<16384, 256, 0, stream>>>(x, xb);
  k_cast_bf16<<<2048, 256, 0, stream>>>(proj_w, w1b);
  k_cast_bf16<<<6144, 256, 0, stream>>>(wf_w, wfwb);
  k_cast_bf16<<<1024, 256, 0, stream>>>(gate_w, gwb);
  k_cast_bf16<<<1024, 256, 0, stream>>>(cls_w1, c1b);
  k_cast_pad<<<1024, 256, 0, stream>>>(cls_w2, c2b, 1000, 1024);

  // G1: y1 = x @ proj_w^T + proj_b  (f32)
  k_gemm_bt<0><<<dim3(8, 64), 256, 0, stream>>>(xb, w1b, proj_b, y1, 8192, 1024, 2048, 1024, nullptr, nullptr);
  // h = gelu(LN(y1))
  k_ln_gelu<<<8192, 256, 0, stream>>>(y1, ln_p_g, ln_p_b, hb);

  // G2 + stage C, chunked over batch (4 x 2048 rows)
  for (int c = 0; c < 4; ++c) {
    k_gemm_bt<1><<<dim3(48, 16), 256, 0, stream>>>(hb + (size_t)c * 2048 * 1024, wfwb, wf_b,
                                                   outc, 2048, 6144, 1024, 6144, nullptr, nullptr);
    k_stage_c<<<2048, 256, 0, stream>>>(outc, ln_g, ln_b, phases, temperature,
                                        supr, supi, c * 2048);
  }

  // self-mod x2 (gate GEMM with fused in-place update)
  for (int it = 0; it < 2; ++it) {
    k_mag<<<8192, 256, 0, stream>>>(supr, supi, magb);
    k_gemm_bt<4><<<dim3(8, 64), 256, 0, stream>>>(magb, gwb, gate_b, nullptr, 8192, 1024, 1024, 1024, supr, supi);
  }

  // top-8 -> probs
  k_topk<<<8192, 256, 0, stream>>>(supr, supi, probs);
  // G4: hid = gelu(probs @ cls_w1^T + cls_b1) (bf16)
  k_gemm_bt<2><<<dim3(8, 64), 256, 0, stream>>>(probs, c1b, cls_b1, hid, 8192, 1024, 1024, 1024, nullptr, nullptr);
  // G5: logits = hid @ cls_w2^T + cls_b2 (f32, Nreal=1000)
  k_gemm_bt<0><<<dim3(8, 64), 256, 0, stream>>>(hid, c2b, cls_b2, out, 8192, 1024, 1024, 1000, nullptr, nullptr);
}

// Round 3
// 653.404 us; speedup vs baseline: 1.1036x; 1.1036x over previous
//
#include <hip/hip_runtime.h>
#include <cstdint>

typedef __attribute__((ext_vector_type(8))) __bf16 bf16x8;
typedef __attribute__((ext_vector_type(4))) __bf16 bf16x4;
typedef __attribute__((ext_vector_type(4))) float f32x4;

__device__ __forceinline__ void gld_lds16(const void* g, void* l) {
  __builtin_amdgcn_global_load_lds(
      (const __attribute__((address_space(1))) void*)g,
      (__attribute__((address_space(3))) void*)l, 16, 0, 0);
}

__device__ __forceinline__ float block_sum(float v, float* scr) {
#pragma unroll
  for (int off = 32; off > 0; off >>= 1) v += __shfl_down(v, off, 64);
  const int w = threadIdx.x >> 6;
  __syncthreads();
  if ((threadIdx.x & 63) == 0) scr[w] = v;
  __syncthreads();
  float s = 0.f;
  const int nw = blockDim.x >> 6;
  for (int i = 0; i < nw; ++i) s += scr[i];
  return s;
}

__device__ __forceinline__ float gelu_exact(float x) {
  return 0.5f * x * (1.f + erff(x * 0.70710678118654752f));
}

// ---------------- casts ----------------
__global__ __launch_bounds__(256) void k_cast_bf16(const float* __restrict__ in,
                                                   __bf16* __restrict__ out) {
  const long i = ((long)blockIdx.x * 256 + threadIdx.x) * 4;
  f32x4 v = *(const f32x4*)(in + i);
  bf16x4 o = {(__bf16)v[0], (__bf16)v[1], (__bf16)v[2], (__bf16)v[3]};
  *(bf16x4*)(out + i) = o;
}

__global__ __launch_bounds__(256) void k_cast_pad(const float* __restrict__ in,
                                                  __bf16* __restrict__ out,
                                                  int rows_real, int cols) {
  const long i = ((long)blockIdx.x * 256 + threadIdx.x) * 4;
  const int row = (int)(i / cols);
  const int col = (int)(i % cols);
  bf16x4 o;
  if (row < rows_real) {
    f32x4 v = *(const f32x4*)(in + (long)row * cols + col);
    o = (bf16x4){(__bf16)v[0], (__bf16)v[1], (__bf16)v[2], (__bf16)v[3]};
  } else {
    o = (bf16x4){(__bf16)0.f, (__bf16)0.f, (__bf16)0.f, (__bf16)0.f};
  }
  *(bf16x4*)(out + i) = o;
}

// ---------------- GEMM: C = A @ B^T + bias ----------------
// A: M x K bf16 row-major; B: N x K bf16 row-major; C: M x Nreal (ldc = Nreal)
// EPI: 0 = f32 store, 1 = bf16 store, 2 = gelu -> bf16,
//      4 = fused self-mod update: supR/supI *= sigmoid(acc+bias)+0.1
// 2-phase double-buffered schedule + XCD-aware column-major swizzle.
template <int EPI>
__global__ __launch_bounds__(256) void k_gemm_bt(
    const __bf16* __restrict__ A, const __bf16* __restrict__ B,
    const float* __restrict__ bias, void* __restrict__ Cout,
    int M, int N, int K, int Nreal,
    float* __restrict__ supR, float* __restrict__ supI) {
  __shared__ __align__(16) __bf16 As[2][128 * 32];
  __shared__ __align__(16) __bf16 Bs[2][128 * 32];
  const int tid = threadIdx.x;
  const int lane = tid & 63;
  const int wid = tid >> 6;
  const int wr = wid >> 1, wc = wid & 1;      // 2x2 wave grid, 64x64 each

  // XCD-aware bijective swizzle over column-major tile order:
  // tile id w = bx*gy + by  (consecutive w share bx -> B-panel reuse in XCD L2)
  const int gx = gridDim.x, gy = gridDim.y;
  const int nwg = gx * gy;
  int bx, by;
  if ((nwg & 7) == 0) {
    const int lin = blockIdx.y * gx + blockIdx.x;
    const int cpx = nwg >> 3;
    const int w = (lin & 7) * cpx + (lin >> 3);
    bx = w / gy;
    by = w % gy;
  } else {
    bx = blockIdx.x;
    by = blockIdx.y;
  }
  const int m0 = by * 128;
  const int n0 = bx * 128;
  const int frow = lane & 15;
  const int fk = (lane >> 4) * 8;
  f32x4 acc[4][4] = {};

  // per-thread staging slot: idx in [0,512) covers 128 rows x 64B
  const int srow = tid >> 1;              // q=0: rows via idx>>2
  (void)srow;
  auto stage = [&](int buf, int k0) {
    const __bf16* Ab = A + (long)m0 * K + k0;
    const __bf16* Bb = B + (long)n0 * K + k0;
#pragma unroll
    for (int q = 0; q < 2; ++q) {
      const int idx = q * 256 + tid;
      const int row = idx >> 2;
      const int col = (idx & 3) * 8;
      gld_lds16(Ab + (long)row * K + col, (char*)(&As[buf][0]) + idx * 16);
      gld_lds16(Bb + (long)row * K + col, (char*)(&Bs[buf][0]) + idx * 16);
    }
  };

  const int nt = K >> 5;  // K/32 tiles
  int cur = 0;
  stage(0, 0);
  __syncthreads();  // compiler drains vmcnt before s_barrier
  for (int t = 0; t < nt; ++t) {
    if (t + 1 < nt) stage(cur ^ 1, (t + 1) << 5);
    bf16x8 af[4], bfr[4];
#pragma unroll
    for (int i = 0; i < 4; ++i) {
      af[i] = *(const bf16x8*)(&As[cur][0] + (wr * 64 + i * 16 + frow) * 32 + fk);
      bfr[i] = *(const bf16x8*)(&Bs[cur][0] + (wc * 64 + i * 16 + frow) * 32 + fk);
    }
#pragma unroll
    for (int im = 0; im < 4; ++im)
#pragma unroll
      for (int in = 0; in < 4; ++in)
        acc[im][in] = __builtin_amdgcn_mfma_f32_16x16x32_bf16(af[im], bfr[in],
                                                              acc[im][in], 0, 0, 0);
    __syncthreads();  // drains next-tile loads; protects buffer overwrite
    cur ^= 1;
  }

  const int crow0 = m0 + wr * 64 + (lane >> 4) * 4;
  const int ccol0 = n0 + wc * 64 + (lane & 15);
#pragma unroll
  for (int in = 0; in < 4; ++in) {
    const int col = ccol0 + in * 16;
    if (col >= Nreal) continue;
    const float bv = bias[col];
#pragma unroll
    for (int im = 0; im < 4; ++im) {
#pragma unroll
      for (int r = 0; r < 4; ++r) {
        const long row = crow0 + im * 16 + r;
        const float v = acc[im][in][r] + bv;
        if (EPI == 0) {
          ((float*)Cout)[row * Nreal + col] = v;
        } else if (EPI == 1) {
          ((__bf16*)Cout)[row * Nreal + col] = (__bf16)v;
        } else if (EPI == 2) {
          ((__bf16*)Cout)[row * Nreal + col] = (__bf16)gelu_exact(v);
        } else {
          const float gmul = 1.f / (1.f + expf(-v)) + 0.1f;
          const long ix = row * Nreal + col;
          supR[ix] *= gmul;
          supI[ix] *= gmul;
        }
      }
    }
  }
}

// ---------------- LN (over 1024) + exact gelu -> bf16 ----------------
__global__ __launch_bounds__(256) void k_ln_gelu(const float* __restrict__ y,
                                                 const float* __restrict__ g,
                                                 const float* __restrict__ b,
                                                 __bf16* __restrict__ h) {
  __shared__ float scr[8];
  const int tid = threadIdx.x;
  const long row = blockIdx.x;
  const float* yr = y + row * 1024;
  f32x4 v = *(const f32x4*)(yr + tid * 4);
  float ls = v[0] + v[1] + v[2] + v[3];
  const float mu = block_sum(ls, scr) * (1.f / 1024.f);
  float lss = 0.f;
#pragma unroll
  for (int j = 0; j < 4; ++j) {
    const float d = v[j] - mu;
    lss += d * d;
  }
  const float var = block_sum(lss, scr) * (1.f / 1024.f);
  const float rstd = rsqrtf(var + 1e-5f);
  bf16x4 o;
#pragma unroll
  for (int j = 0; j < 4; ++j) {
    const int c = tid * 4 + j;
    const float t = (v[j] - mu) * rstd * g[c] + b[c];
    o[j] = (__bf16)gelu_exact(t);
  }
  *(bf16x4*)(h + row * 1024 + tid * 4) = o;
}

// ---------------- stage C ----------------
__global__ __launch_bounds__(256) void k_stage_c(
    const __bf16* __restrict__ outb, const float* __restrict__ ln_g,
    const float* __restrict__ ln_b, const float* __restrict__ phases,
    const float* __restrict__ temp, float* __restrict__ supr,
    float* __restrict__ supi, int b0) {
  __shared__ float wrs[3][1024];
  __shared__ float wis[3][1024];
  __shared__ float gbuf[2048];
  __shared__ float scr[8];
  const int tid = threadIdx.x;
  const long b = blockIdx.x;

#pragma unroll 1
  for (int s = 0; s < 3; ++s) {
    const __bf16* src = outb + b * 6144 + s * 2048;
    bf16x8 v8 = *(const bf16x8*)(src + tid * 8);
    float x[8];
#pragma unroll
    for (int j = 0; j < 8; ++j) x[j] = (float)v8[j];
    float ls = 0.f;
#pragma unroll
    for (int j = 0; j < 8; ++j) ls += x[j];
    const float mu = block_sum(ls, scr) * (1.f / 2048.f);
    float lss = 0.f;
#pragma unroll
    for (int j = 0; j < 8; ++j) {
      const float d = x[j] - mu;
      lss += d * d;
    }
    const float var = block_sum(lss, scr) * (1.f / 2048.f);
    const float rstd = rsqrtf(var + 1e-5f);
    const float* lg = ln_g + s * 2048;
    const float* lb = ln_b + s * 2048;
    float nsq = 0.f;
#pragma unroll
    for (int j = 0; j < 8; ++j) {
      const int e = tid * 8 + j;
      const float yv = (x[j] - mu) * rstd * lg[e] + lb[e];
      const float gv = expf(-yv * yv);
      gbuf[e] = gv;
      nsq += gv * gv;
    }
    const float normsq = block_sum(nsq, scr) + 1e-8f; // syncs make gbuf visible
    const float factor = sqrtf(2.25f / normsq);
    const float ph = phases[s];
    const float cs = cosf(ph), sn = sinf(ph);
#pragma unroll
    for (int j = 0; j < 4; ++j) {
      const int h = j * 256 + tid;
      const float a = gbuf[h] * factor;
      const float bb = gbuf[h + 1024] * factor;
      wrs[s][h] = a * cs - bb * sn;
      wis[s][h] = a * sn + bb * cs;
    }
    __syncthreads();
  }

  float mr[4];
  float pmn = 0.f;
#pragma unroll
  for (int j = 0; j < 4; ++j) {
    const int h = j * 256 + tid;
    const float m = (wrs[0][h] + wrs[1][h] + wrs[2][h]) * (1.f / 3.f);
    mr[j] = m;
    pmn += m * m;
  }
  const float mnorm = sqrtf(block_sum(pmn, scr)) + 1e-8f;
  float csim[3];
#pragma unroll 1
  for (int s = 0; s < 3; ++s) {
    float pd = 0.f, pw = 0.f;
#pragma unroll
    for (int j = 0; j < 4; ++j) {
      const int h = j * 256 + tid;
      const float w = wrs[s][h];
      pd += w * mr[j];
      pw += w * w;
    }
    const float dot = block_sum(pd, scr);
    const float wn = sqrtf(block_sum(pw, scr)) + 1e-8f;
    csim[s] = dot / (wn * mnorm);
  }
  const float T = temp[0];
  const float t0 = csim[0] / T, t1 = csim[1] / T, t2 = csim[2] / T;
  const float mx = fmaxf(t0, fmaxf(t1, t2));
  const float e0 = expf(t0 - mx), e1 = expf(t1 - mx), e2 = expf(t2 - mx);
  const float inv = 1.f / (e0 + e1 + e2);
  const float w0 = e0 * inv, w1 = e1 * inv, w2 = e2 * inv;
#pragma unroll
  for (int j = 0; j < 4; ++j) {
    const int h = j * 256 + tid;
    supr[(long)(b0 + b) * 1024 + h] = wrs[0][h] * w0 + wrs[1][h] * w1 + wrs[2][h] * w2;
    supi[(long)(b0 + b) * 1024 + h] = wis[0][h] * w0 + wis[1][h] * w1 + wis[2][h] * w2;
  }
}

// ---------------- mag ----------------
__global__ __launch_bounds__(256) void k_mag(const float* __restrict__ sr,
                                             const float* __restrict__ si,
                                             __bf16* __restrict__ mag) {
  const long i = ((long)blockIdx.x * 256 + threadIdx.x) * 4;
  f32x4 r = *(const f32x4*)(sr + i);
  f32x4 im = *(const f32x4*)(si + i);
  bf16x4 o;
#pragma unroll
  for (int j = 0; j < 4; ++j)
    o[j] = (__bf16)sqrtf(r[j] * r[j] + im[j] * im[j] + 1e-8f);
  *(bf16x4*)(mag + i) = o;
}

// ---------------- top-8 mask + normalize -> probs (bf16) ----------------
__global__ __launch_bounds__(256) void k_topk(const float* __restrict__ supr,
                                              const float* __restrict__ supi,
                                              __bf16* __restrict__ probs) {
  __shared__ float vals[1024];
  __shared__ float redv[4];
  __shared__ int redi[4];
  __shared__ int selidx[8];
  __shared__ float ssum;
  const int tid = threadIdx.x;
  const long b = blockIdx.x;
  float myv[4];
#pragma unroll
  for (int j = 0; j < 4; ++j) {
    const int h = j * 256 + tid;
    const float r = supr[b * 1024 + h];
    const float im = supi[b * 1024 + h];
    const float v = r * r + im * im;
    myv[j] = v;
    vals[h] = v;
  }
  if (tid == 0) ssum = 0.f;
  __syncthreads();
  for (int it = 0; it < 8; ++it) {
    float bv = -1.f;
    int bi = 1 << 30;
#pragma unroll
    for (int j = 0; j < 4; ++j) {
      const int h = j * 256 + tid;
      const float v = vals[h];
      if (v > bv || (v == bv && h < bi)) { bv = v; bi = h; }
    }
#pragma unroll
    for (int off = 32; off > 0; off >>= 1) {
      const float ov = __shfl_down(bv, off, 64);
      const int oi = __shfl_down(bi, off, 64);
      if (ov > bv || (ov == bv && oi < bi)) { bv = ov; bi = oi; }
    }
    if ((tid & 63) == 0) { redv[tid >> 6] = bv; redi[tid >> 6] = bi; }
    __syncthreads();
    if (tid == 0) {
      float fv = redv[0];
      int fi = redi[0];
      for (int w = 1; w < 4; ++w)
        if (redv[w] > fv || (redv[w] == fv && redi[w] < fi)) { fv = redv[w]; fi = redi[w]; }
      selidx[it] = fi;
      vals[fi] = -1.f;
      ssum += fv;
    }
    __syncthreads();
  }
  const float denom = 1.f / (ssum + 1e-8f);
#pragma unroll
  for (int j = 0; j < 4; ++j) {
    const int h = j * 256 + tid;
    float p = 0.f;
#pragma unroll
    for (int t = 0; t < 8; ++t)
      if (selidx[t] == h) p = myv[j] * denom;
    probs[b * 1024 + h] = (__bf16)p;
  }
}

extern "C" void kernel_launch(void* const* d_in, const int* in_sizes, int n_in,
                              void* d_out, int out_size, void* d_ws, size_t ws_size,
                              hipStream_t stream) {
  const float* x      = (const float*)d_in[0];
  const float* proj_w = (const float*)d_in[1];
  const float* proj_b = (const float*)d_in[2];
  const float* ln_p_g = (const float*)d_in[3];
  const float* ln_p_b = (const float*)d_in[4];
  const float* wf_w   = (const float*)d_in[5];
  const float* wf_b   = (const float*)d_in[6];
  const float* ln_g   = (const float*)d_in[7];
  const float* ln_b   = (const float*)d_in[8];
  const float* temperature = (const float*)d_in[9];
  const float* phases = (const float*)d_in[10];
  const float* gate_w = (const float*)d_in[11];
  const float* gate_b = (const float*)d_in[12];
  const float* cls_w1 = (const float*)d_in[13];
  const float* cls_b1 = (const float*)d_in[14];
  const float* cls_w2 = (const float*)d_in[15];
  const float* cls_b2 = (const float*)d_in[16];
  float* out = (float*)d_out;
  (void)in_sizes; (void)n_in; (void)out_size; (void)ws_size;

  // 130MB lifetime-aliased layout (regions never overlap while live):
  //   A [0,32M):   xb (casts,G1)            -> supr (stage_c..topk)
  //   B [32,64M):  y1 (G1,ln) -> outc 24MB (chunk loop) -> magb@+0 / probs@+16M / hid@+0
  //   C [64,96M):  w1b@+0 4MB (casts,G1)    -> supi (stage_c..topk)
  //   [96,108M):   wfwb     [108,124M): hb(h)    [124,130M): gwb,c1b,c2b
  char* ws = (char*)d_ws;
  const size_t MB = 1024 * 1024;
  __bf16* xb    = (__bf16*)(ws + 0);
  float*  supr  = (float*)(ws + 0);
  float*  y1    = (float*)(ws + 32 * MB);
  __bf16* outc  = (__bf16*)(ws + 32 * MB);
  __bf16* magb  = (__bf16*)(ws + 32 * MB);
  __bf16* hid   = (__bf16*)(ws + 32 * MB);
  __bf16* probs = (__bf16*)(ws + 48 * MB);
  __bf16* w1b   = (__bf16*)(ws + 64 * MB);
  float*  supi  = (float*)(ws + 64 * MB);
  __bf16* wfwb  = (__bf16*)(ws + 96 * MB);
  __bf16* hb    = (__bf16*)(ws + 108 * MB);
  __bf16* gwb   = (__bf16*)(ws + 124 * MB);
  __bf16* c1b   = (__bf16*)(ws + 126 * MB);
  __bf16* c2b   = (__bf16*)(ws + 128 * MB);

  // casts
  k_cast_bf16<<<16384, 256, 0, stream>>>(x, xb);
  k_cast_bf16<<<2048, 256, 0, stream>>>(proj_w, w1b);
  k_cast_bf16<<<6144, 256, 0, stream>>>(wf_w, wfwb);
  k_cast_bf16<<<1024, 256, 0, stream>>>(gate_w, gwb);
  k_cast_bf16<<<1024, 256, 0, stream>>>(cls_w1, c1b);
  k_cast_pad<<<1024, 256, 0, stream>>>(cls_w2, c2b, 1000, 1024);

  // G1: y1 = x @ proj_w^T + proj_b  (f32)
  k_gemm_bt<0><<<dim3(8, 64), 256, 0, stream>>>(xb, w1b, proj_b, y1, 8192, 1024, 2048, 1024, nullptr, nullptr);
  // h = gelu(LN(y1))
  k_ln_gelu<<<8192, 256, 0, stream>>>(y1, ln_p_g, ln_p_b, hb);

  // G2 + stage C, chunked over batch (4 x 2048 rows)
  for (int c = 0; c < 4; ++c) {
    k_gemm_bt<1><<<dim3(48, 16), 256, 0, stream>>>(hb + (size_t)c * 2048 * 1024, wfwb, wf_b,
                                                   outc, 2048, 6144, 1024, 6144, nullptr, nullptr);
    k_stage_c<<<2048, 256, 0, stream>>>(outc, ln_g, ln_b, phases, temperature,
                                        supr, supi, c * 2048);
  }

  // self-mod x2 (gate GEMM with fused in-place update)
  for (int it = 0; it < 2; ++it) {
    k_mag<<<8192, 256, 0, stream>>>(supr, supi, magb);
    k_gemm_bt<4><<<dim3(8, 64), 256, 0, stream>>>(magb, gwb, gate_b, nullptr, 8192, 1024, 1024, 1024, supr, supi);
  }

  // top-8 -> probs
  k_topk<<<8192, 256, 0, stream>>>(supr, supi, probs);
  // G4: hid = gelu(probs @ cls_w1^T + cls_b1) (bf16)
  k_gemm_bt<2><<<dim3(8, 64), 256, 0, stream>>>(probs, c1b, cls_b1, hid, 8192, 1024, 1024, 1024, nullptr, nullptr);
  // G5: logits = hid @ cls_w2^T + cls_b2 (f32, Nreal=1000)
  k_gemm_bt<0><<<dim3(8, 64), 256, 0, stream>>>(hid, c2b, cls_b2, out, 8192, 1024, 1024, 1000, nullptr, nullptr);
}